// Round 1
// 332.772 us; speedup vs baseline: 1.0636x; 1.0636x over previous
//
#include <hip/hip_runtime.h>

// PrecRec: confusion-matrix counts over 10 sigmoid thresholds.
//
// R7: cache-policy experiment on the R3/R6 structure.
// R6 established: 5 structurally different kernels all pin at 2.8-3.1 TB/s
// effective read with no pipe >27% busy. New localization of the wall:
//   - m13 copy read-component is ALSO ~3.15 TB/s (6.29 total / 2) -> same wall
//   - m56 L2-resident reads hit 36.9 TB/s -> CU<->L2 path is NOT the wall
//   - L3-served replays run at identical speed -> fills from L3 cost the
//     same as fills from HBM
// => hypothesis: per-XCD L2 fill/allocation rate limit (~390 GB/s/XCD =
//    ~1.3 x 128B line-fills/cycle). Every prior structure allocated every
//    byte into L2 once -> identical ceiling.
// Lever: non-temporal loads (global_load_dwordx4 ... nt). Data is strictly
// streaming (each byte read once, zero reuse), so no-allocate/evict-first is
// semantically correct. If the fill-rate model holds, dur 130 -> 70-95 us;
// if unchanged, the ceiling is at/above the fabric and 130 us (97% of the
// 402.7 MB / 3.15 TB/s = 128 us floor) is the roofline.
//
// Structure otherwise identical to R6: wave-chunked batch-4 loads, cheap
// sigmoid bucketing (absmax 0.0 verified in R5), packed u64 histograms
// (level-1 5-bit x 11, cap 31; level-2 10-bit x 11, cap 1023), suffix sums.

#define NTHR 10
#define NBKT 11            // bucket = #thresholds passed, 0..10
#define NCNT 22            // ws: [0..10]=P-bucket counts, [11..21]=TP-bucket
#define WS_STRIDE 16       // 64 B between counters

typedef unsigned long long u64;
typedef unsigned u32;
typedef float __attribute__((ext_vector_type(4))) f32x4;
typedef int   __attribute__((ext_vector_type(4))) i32x4;

__device__ __forceinline__ unsigned wave_reduce_add(unsigned v) {
#pragma unroll
    for (int off = 32; off > 0; off >>= 1)
        v += __shfl_down(v, off, 64);
    return v;
}

__global__ __launch_bounds__(64) void zero_ws_kernel(u32* __restrict__ ws) {
    int i = threadIdx.x;
    if (i < NCNT) ws[i * WS_STRIDE] = 0u;
}

__device__ __forceinline__ void acc_elem(float x, u32 mm, u32 tt, u64& hP, u64& hT) {
    u32 mt = mm & tt;
    // bucket = #(sigmoid(x) > j/11) = min(10, floor(11*sigmoid(x)))
    float e = __expf(-x);                          // v_mul + v_exp
    float s = __builtin_amdgcn_rcpf(1.0f + e);     // v_add + v_rcp
    int bi = (int)(s * 11.0f);                     // v_mul + v_cvt (s>=0)
    u32 b = (u32)(bi > 10 ? 10 : bi);              // guard s==1.0
    u32 sh = b * 5u;
    hP += (u64)mm << sh;
    hT += (u64)mt << sh;
}

__device__ __forceinline__ void acc_vec(const f32x4& p, const i32x4& m, const i32x4& t,
                                        u64& hP, u64& hT) {
    acc_elem(p.x, (u32)m.x, (u32)t.x, hP, hT);
    acc_elem(p.y, (u32)m.y, (u32)t.y, hP, hT);
    acc_elem(p.z, (u32)m.z, (u32)t.z, hP, hT);
    acc_elem(p.w, (u32)m.w, (u32)t.w, hP, hT);
}

__device__ __forceinline__ void flush_hist(u64& hP, u64& hT,
                                           u64& Plo, u64& Phi, u64& Tlo, u64& Thi) {
#pragma unroll
    for (int b = 0; b < 6; ++b) {
        Plo += (u64)((u32)(hP >> (5 * b)) & 31u) << (10 * b);
        Tlo += (u64)((u32)(hT >> (5 * b)) & 31u) << (10 * b);
    }
#pragma unroll
    for (int b = 6; b < NBKT; ++b) {
        Phi += (u64)((u32)(hP >> (5 * b)) & 31u) << (10 * (b - 6));
        Thi += (u64)((u32)(hT >> (5 * b)) & 31u) << (10 * (b - 6));
    }
    hP = 0ull; hT = 0ull;
}

__global__ __launch_bounds__(256) void count_kernel(
        const f32x4* __restrict__ pred4,
        const i32x4* __restrict__ mask4,
        const i32x4* __restrict__ targ4,
        const float* __restrict__ pred,
        const int*   __restrict__ mask,
        const int*   __restrict__ targ,
        u32* __restrict__ ws, int nvec, int n) {
    u64 Plo = 0ull, Phi = 0ull, Tlo = 0ull, Thi = 0ull;

    const int tid    = blockIdx.x * blockDim.x + threadIdx.x;
    const int lane   = tid & 63;
    const int waveId = tid >> 6;
    const int totalWaves = (gridDim.x * blockDim.x) >> 6;
    const int strideG    = totalWaves << 8;     // waves * 256 groups/iter

    for (int base = waveId << 8; base < nvec; base += strideG) {
        u64 hP = 0ull, hT = 0ull;
        if (base + 256 <= nvec) {
            // 12 independent 16B non-temporal loads (no L2/L3 allocation)
            f32x4 p0 = __builtin_nontemporal_load(pred4 + base +       lane);
            f32x4 p1 = __builtin_nontemporal_load(pred4 + base +  64 + lane);
            f32x4 p2 = __builtin_nontemporal_load(pred4 + base + 128 + lane);
            f32x4 p3 = __builtin_nontemporal_load(pred4 + base + 192 + lane);
            i32x4 m0 = __builtin_nontemporal_load(mask4 + base +       lane);
            i32x4 m1 = __builtin_nontemporal_load(mask4 + base +  64 + lane);
            i32x4 m2 = __builtin_nontemporal_load(mask4 + base + 128 + lane);
            i32x4 m3 = __builtin_nontemporal_load(mask4 + base + 192 + lane);
            i32x4 t0 = __builtin_nontemporal_load(targ4 + base +       lane);
            i32x4 t1 = __builtin_nontemporal_load(targ4 + base +  64 + lane);
            i32x4 t2 = __builtin_nontemporal_load(targ4 + base + 128 + lane);
            i32x4 t3 = __builtin_nontemporal_load(targ4 + base + 192 + lane);
            acc_vec(p0, m0, t0, hP, hT);
            acc_vec(p1, m1, t1, hP, hT);
            acc_vec(p2, m2, t2, hP, hT);
            acc_vec(p3, m3, t3, hP, hT);
        } else {
#pragma unroll
            for (int c = 0; c < 4; ++c) {
                int g = base + (c << 6) + lane;
                if (g < nvec) {
                    f32x4 p = __builtin_nontemporal_load(pred4 + g);
                    i32x4 m = __builtin_nontemporal_load(mask4 + g);
                    i32x4 t = __builtin_nontemporal_load(targ4 + g);
                    acc_vec(p, m, t, hP, hT);
                }
            }
        }
        flush_hist(hP, hT, Plo, Phi, Tlo, Thi);   // <=16 elems per 5-bit field
    }

    // scalar tail (n % 4)
    {
        int i = nvec * 4 + tid;
        if (i < n) {
            u64 hP = 0ull, hT = 0ull;
            acc_elem(pred[i], (u32)mask[i], (u32)targ[i], hP, hT);
            flush_hist(hP, hT, Plo, Phi, Tlo, Thi);
        }
    }

    // unpack level-2 (10-bit fields; per-thread elems <= 64 << 1023 cap)
    u32 vals[NCNT];
#pragma unroll
    for (int b = 0; b < 6; ++b) {
        vals[b]        = (u32)(Plo >> (10 * b)) & 1023u;
        vals[NBKT + b] = (u32)(Tlo >> (10 * b)) & 1023u;
    }
#pragma unroll
    for (int b = 6; b < NBKT; ++b) {
        vals[b]        = (u32)(Phi >> (10 * (b - 6))) & 1023u;
        vals[NBKT + b] = (u32)(Thi >> (10 * (b - 6))) & 1023u;
    }
#pragma unroll
    for (int c = 0; c < NCNT; ++c) vals[c] = wave_reduce_add(vals[c]);

    __shared__ u32 partial[4][NCNT];
    const int wave = threadIdx.x >> 6;
    if ((threadIdx.x & 63) == 0) {
#pragma unroll
        for (int c = 0; c < NCNT; ++c) partial[wave][c] = vals[c];
    }
    __syncthreads();
    if (threadIdx.x < NCNT) {
        u32 s = partial[0][threadIdx.x] + partial[1][threadIdx.x] +
                partial[2][threadIdx.x] + partial[3][threadIdx.x];
        atomicAdd(&ws[threadIdx.x * WS_STRIDE], s);
    }
}

__global__ __launch_bounds__(64) void finalize_kernel(const u32* __restrict__ ws,
                                                      float* __restrict__ out) {
    int j = threadIdx.x;
    if (j < NTHR) {
        u32 totM = 0u, totT = 0u, p = 0u, tp = 0u;
#pragma unroll
        for (int b = 0; b < NBKT; ++b) {
            u32 vP = ws[b * WS_STRIDE];
            u32 vT = ws[(NBKT + b) * WS_STRIDE];
            totM += vP; totT += vT;
            if (b > j) { p += vP; tp += vT; }
        }
        u32 fp = p - tp;
        u32 fn = totT - tp;
        u32 tn = totM - p - fn;
        out[j]            = (float)tp;
        out[NTHR + j]     = (float)fp;
        out[2 * NTHR + j] = (float)tn;
        out[3 * NTHR + j] = (float)fn;
    }
}

extern "C" void kernel_launch(void* const* d_in, const int* in_sizes, int n_in,
                              void* d_out, int out_size, void* d_ws, size_t ws_size,
                              hipStream_t stream) {
    const float* pred = (const float*)d_in[0];
    const int*   mask = (const int*)d_in[1];
    const int*   targ = (const int*)d_in[2];
    u32*         ws   = (u32*)d_ws;
    float*       out  = (float*)d_out;

    const int n    = in_sizes[0];
    const int nvec = n / 4;

    zero_ws_kernel<<<1, 64, 0, stream>>>(ws);

    // 2048 blocks x 256 = 8192 waves; 4 iterations/wave at this size.
    const int blocks = 2048;
    count_kernel<<<blocks, 256, 0, stream>>>(
        (const f32x4*)pred, (const i32x4*)mask, (const i32x4*)targ,
        pred, mask, targ, ws, nvec, n);

    finalize_kernel<<<1, 64, 0, stream>>>(ws, out);
}